// Round 16
// baseline (854.375 us; speedup 1.0000x reference)
//
#include <hip/hip_runtime.h>
#include <stdint.h>

#define BB 8
#define NN 4096
#define CC 64
#define MM 1024
#define EE (BB*MM)   // 8192 centroids
#define KK 64        // max neighbors
#define F3 256       // output channels
#define SM 104       // msg LDS stride (elements)
#define SH 136       // h LDS stride (elements)
#define CAP 768      // candidate buffer
#define NWORK 248    // worker blocks (2 teams each): capacity 248*0.0409 = 10.1/us ~= production 10.9

typedef __bf16 bf16x8 __attribute__((ext_vector_type(8)));
typedef float floatx4 __attribute__((ext_vector_type(4)));

// ---- wave64 reductions via DPP (round-3-verified) ----
#define DPP_MAXSTEP(ctrl, rmask) { \
    unsigned o = (unsigned)__builtin_amdgcn_update_dpp(0, (int)v, ctrl, rmask, 0xf, false); \
    v = v > o ? v : o; }
__device__ __forceinline__ unsigned wave_umax_u32(unsigned v) {
  DPP_MAXSTEP(0x111, 0xf)
  DPP_MAXSTEP(0x112, 0xf)
  DPP_MAXSTEP(0x114, 0xf)
  DPP_MAXSTEP(0x118, 0xf)
  DPP_MAXSTEP(0x142, 0xa)
  DPP_MAXSTEP(0x143, 0xc)
  return (unsigned)__builtin_amdgcn_readlane((int)v, 63);
}
#define DPP_MINSTEP(ctrl, rmask) { \
    unsigned o = (unsigned)__builtin_amdgcn_update_dpp((int)0xffffffffu, (int)v, ctrl, rmask, 0xf, false); \
    v = v < o ? v : o; }
__device__ __forceinline__ unsigned wave_umin_u32(unsigned v) {
  DPP_MINSTEP(0x111, 0xf)
  DPP_MINSTEP(0x112, 0xf)
  DPP_MINSTEP(0x114, 0xf)
  DPP_MINSTEP(0x118, 0xf)
  DPP_MINSTEP(0x142, 0xa)
  DPP_MINSTEP(0x143, 0xc)
  return (unsigned)__builtin_amdgcn_readlane((int)v, 63);
}

// ---- MLP item body (round-3-verified numerics). EXACTLY 6 __syncthreads. ----
// tt is the team-local thread id in [0,512).
__device__ __forceinline__ void mlp_item(
    int e, int b, int tt,
    const float* __restrict__ x, const float4* __restrict__ pos4,
    const float* __restrict__ ctr, const int* __restrict__ fpsIdx,
    const __bf16* __restrict__ W1t, const __bf16* __restrict__ W2t,
    const __bf16* __restrict__ W3t,
    const float* __restrict__ b1, const float* __restrict__ b2,
    const float* __restrict__ b3,
    float* __restrict__ outX, float* __restrict__ outP,
    float* __restrict__ outB, float* __restrict__ outS,
    __bf16* sMsg, __bf16* sH, int* sSel, int* sCnt) {
  // caller must have set *sCnt = 0 and issued __syncthreads()
  unsigned long long* sDI = (unsigned long long*)sMsg;  // [CAP] packed (d2bits<<32 | idx)
  const int lane = tt & 63, wv = tt >> 6;

  const float cx = ctr[(long)e * 3 + 0];
  const float cy = ctr[(long)e * 3 + 1];
  const float cz = ctr[(long)e * 3 + 2];
  if (tt < 3) outP[(long)e * 3 + tt] = ctr[(long)e * 3 + tt];
  if (tt == 3) { outB[e] = (float)b; outS[e] = (float)(b * NN + fpsIdx[e]); }
  const float R2 = (float)(0.2 * 0.2);

  // Phase A: scan 4096 points; ballot-compact candidates to LDS.
#pragma unroll
  for (int q = 0; q < NN / 512; ++q) {
    const int p = tt + q * 512;
    const float4 P = pos4[b * NN + p];
    const float dx = __fsub_rn(cx, P.x);
    const float dy = __fsub_rn(cy, P.y);
    const float dz = __fsub_rn(cz, P.z);
    const float d2 = __fadd_rn(__fadd_rn(__fmul_rn(dx, dx), __fmul_rn(dy, dy)), __fmul_rn(dz, dz));
    const bool v = d2 < R2;
    const unsigned long long mask = __ballot(v);
    int wbase = 0;
    if (lane == 0 && mask) wbase = atomicAdd(sCnt, (int)__popcll(mask));
    wbase = __shfl(wbase, 0);
    if (v) {
      const int off = wbase + (int)__popcll(mask & ((1ull << lane) - 1ull));
      if (off < CAP)
        sDI[off] = ((unsigned long long)__float_as_uint(d2) << 32) | (unsigned)p;
    }
  }
  __syncthreads();                                   // barrier 1
  int cnt = *sCnt; cnt = cnt > CAP ? CAP : cnt;
  const int nsel = cnt < KK ? cnt : KK;

  // Phase B: parallel rank selection.
  for (int i = tt; i < cnt; i += 512) {
    const unsigned long long my = sDI[i];
    int rank = 0;
#pragma unroll 8
    for (int j = 0; j < cnt; ++j) rank += (sDI[j] < my) ? 1 : 0;
    if (rank < KK) sSel[rank] = (int)(unsigned)(my & 0xffffffffu);
  }
  __syncthreads();                                   // barrier 2
  cnt = nsel;

  // Phase C: stage msg tile into LDS as bf16.
  {
    const int r = tt >> 3, p = tt & 7;
    float4 a = make_float4(0.f, 0.f, 0.f, 0.f), c4 = a;
    if (r < cnt) {
      const float* xr = x + (long)(b * NN + sSel[r]) * CC + p * 8;
      a  = *(const float4*)xr;
      c4 = *(const float4*)(xr + 4);
    }
    __bf16 o[8] = {(__bf16)a.x, (__bf16)a.y, (__bf16)a.z, (__bf16)a.w,
                   (__bf16)c4.x, (__bf16)c4.y, (__bf16)c4.z, (__bf16)c4.w};
    *(uint4*)&sMsg[r * SM + p * 8] = *(uint4*)o;
  }
  if (tt < 64) {
    const int r = tt;
    __bf16 d0 = (__bf16)0.0f, d1 = (__bf16)0.0f, d2v = (__bf16)0.0f;
    if (r < cnt) {
      const float4 P = pos4[b * NN + sSel[r]];
      d0  = (__bf16)__fsub_rn(P.x, cx);
      d1  = (__bf16)__fsub_rn(P.y, cy);
      d2v = (__bf16)__fsub_rn(P.z, cz);
    }
    sMsg[r * SM + 64] = d0;
    sMsg[r * SM + 65] = d1;
    sMsg[r * SM + 66] = d2v;
    for (int c = 67; c < SM; ++c) sMsg[r * SM + c] = (__bf16)0.0f;
  }
  __syncthreads();                                   // barrier 3

  const int l15 = lane & 15, quad = lane >> 4;
  // layer 1
  {
    floatx4 acc[4] = {};
    const __bf16* wrow = W1t + (wv * 16 + l15) * 96;
#pragma unroll
    for (int ks = 0; ks < 3; ++ks) {
      const bf16x8 bfrag = *(const bf16x8*)(wrow + ks * 32 + quad * 8);
#pragma unroll
      for (int mt = 0; mt < 4; ++mt) {
        const bf16x8 afrag = *(const bf16x8*)&sMsg[(mt * 16 + l15) * SM + ks * 32 + quad * 8];
        acc[mt] = __builtin_amdgcn_mfma_f32_16x16x32_bf16(afrag, bfrag, acc[mt], 0, 0, 0);
      }
    }
    const int col = wv * 16 + l15;
    const float bias = b1[col];
#pragma unroll
    for (int mt = 0; mt < 4; ++mt)
#pragma unroll
      for (int rg = 0; rg < 4; ++rg) {
        const int row = mt * 16 + quad * 4 + rg;
        float v = acc[mt][rg] + bias;
        v = v > 0.0f ? v : 0.0f;
        sH[row * SH + col] = (__bf16)v;
      }
  }
  __syncthreads();                                   // barrier 4
  // layer 2 (in place on sH)
  {
    floatx4 acc[4] = {};
    const __bf16* wrow = W2t + (wv * 16 + l15) * 128;
#pragma unroll
    for (int ks = 0; ks < 4; ++ks) {
      const bf16x8 bfrag = *(const bf16x8*)(wrow + ks * 32 + quad * 8);
#pragma unroll
      for (int mt = 0; mt < 4; ++mt) {
        const bf16x8 afrag = *(const bf16x8*)&sH[(mt * 16 + l15) * SH + ks * 32 + quad * 8];
        acc[mt] = __builtin_amdgcn_mfma_f32_16x16x32_bf16(afrag, bfrag, acc[mt], 0, 0, 0);
      }
    }
    __syncthreads();                                 // barrier 5
    const int col = wv * 16 + l15;
    const float bias = b2[col];
#pragma unroll
    for (int mt = 0; mt < 4; ++mt)
#pragma unroll
      for (int rg = 0; rg < 4; ++rg) {
        const int row = mt * 16 + quad * 4 + rg;
        float v = acc[mt][rg] + bias;
        v = v > 0.0f ? v : 0.0f;
        sH[row * SH + col] = (__bf16)v;
      }
  }
  __syncthreads();                                   // barrier 6
  // layer 3 + fused masked max (no barriers)
  {
    floatx4 acc[2][4] = {};
#pragma unroll
    for (int ks = 0; ks < 4; ++ks) {
      bf16x8 afrag[4];
#pragma unroll
      for (int mt = 0; mt < 4; ++mt)
        afrag[mt] = *(const bf16x8*)&sH[(mt * 16 + l15) * SH + ks * 32 + quad * 8];
#pragma unroll
      for (int i = 0; i < 2; ++i) {
        const bf16x8 bfrag = *(const bf16x8*)(W3t + ((wv * 2 + i) * 16 + l15) * 128 + ks * 32 + quad * 8);
#pragma unroll
        for (int mt = 0; mt < 4; ++mt)
          acc[i][mt] = __builtin_amdgcn_mfma_f32_16x16x32_bf16(afrag[mt], bfrag, acc[i][mt], 0, 0, 0);
      }
    }
#pragma unroll
    for (int i = 0; i < 2; ++i) {
      const int col = (wv * 2 + i) * 16 + l15;
      const float bias = b3[col];
      float mx = 0.0f;
#pragma unroll
      for (int mt = 0; mt < 4; ++mt)
#pragma unroll
        for (int rg = 0; rg < 4; ++rg) {
          const int row = mt * 16 + quad * 4 + rg;
          float v = acc[i][mt][rg] + bias;
          v = v > 0.0f ? v : 0.0f;
          if (row < cnt) mx = fmaxf(mx, v);
        }
      mx = fmaxf(mx, __shfl_xor(mx, 16));
      mx = fmaxf(mx, __shfl_xor(mx, 32));
      if (quad == 0) outX[(long)e * F3 + col] = mx;
    }
  }
}

// ctl layout (dwords; each counter on its own 128B line); memset 2048 B:
#define CTL_PREP 0
#define CTL_PROG(g) (32*((g)+1))
#define CTL_QHEAD 320
#define CTL_DONE 352

// ---- Kernel A: 1024-thread blocks, 82 KB pad => 1 block/CU (r11-verified).
//      blocks 0..7: FPS producers (r13-exact loop). blocks 8..255: workers with
//      TWO 512-thread teams each claiming its own item (paired fetch_add(2)).
//      r15 measured: two-team per-CU throughput 0.0409 items/us (+26% vs
//      one-team 0.0323; L 31->49us from team contention). r15's grid-188 gave
//      back the gain; this round restores grid 256 (r13 vs r15 A/B: FPS speed
//      insensitive to 188-vs-248 busy CUs). Capacity 248*0.0409=10.1/us ~=
//      production 10.9/us => backlog ~600 => drain ~18us.
__global__ __launch_bounds__(1024) void fps_overlap_kernel(
    const float* __restrict__ x, const float* __restrict__ pos,
    const float* __restrict__ W1, const float* __restrict__ b1,
    const float* __restrict__ W2, const float* __restrict__ b2,
    const float* __restrict__ W3, const float* __restrict__ b3,
    int* __restrict__ fpsIdx, float* __restrict__ ctr,
    __bf16* __restrict__ W1t, __bf16* __restrict__ W2t, __bf16* __restrict__ W3t,
    float4* __restrict__ pos4, unsigned* __restrict__ ctl,
    float* __restrict__ outX, float* __restrict__ outP,
    float* __restrict__ outB, float* __restrict__ outS) {
  __shared__ __align__(16) unsigned char sBuf[83968];  // 82 KB pad => exclusive CU
  __shared__ int sClaimA;

  const int t = threadIdx.x;
  const int blk = blockIdx.x;

  if (blk < BB) {
    // ================= FPS producer (graph g), r13-exact loop =================
    const int g = blk;
    float4* sP4 = (float4*)sBuf;
    unsigned long long* sRed = (unsigned long long*)(sBuf + 65536);  // [2][4]

    // prep slice: 94208 items over 8 blocks = 11776 each (1024-thread stride)
    for (int k = g * 11776 + t; k < (g + 1) * 11776; k += 1024) {
      if (k < 12288) {
        const int n = k / 96, kk = k % 96;
        W1t[k] = (kk < 67) ? (__bf16)W1[kk * 128 + n] : (__bf16)0.0f;
      } else if (k < 28672) {
        const int i = k - 12288, n = i / 128, kk = i % 128;
        W2t[i] = (__bf16)W2[kk * 128 + n];
      } else if (k < 61440) {
        const int i = k - 28672, n = i / 128, kk = i % 128;
        W3t[i] = (__bf16)W3[kk * 256 + n];
      } else {
        const int i = k - 61440;
        pos4[i] = make_float4(pos[(long)i * 3 + 0], pos[(long)i * 3 + 1],
                              pos[(long)i * 3 + 2], 0.0f);
      }
    }
    __threadfence();
    __syncthreads();
    if (t == 0)
      __hip_atomic_fetch_add(&ctl[CTL_PREP], 1u, __ATOMIC_RELEASE, __HIP_MEMORY_SCOPE_AGENT);

    __builtin_amdgcn_s_setprio(1);

    const int lane = t & 63, wv = t >> 6;    // working waves 0..3 (t<256)
    float px[16], py[16], pz[16], mind[16];
    if (t < 256) {
#pragma unroll
      for (int j = 0; j < 16; ++j) {
        const int p = t + (j << 8);
        const long base = ((long)g * NN + p) * 3;
        px[j] = pos[base + 0];
        py[j] = pos[base + 1];
        pz[j] = pos[base + 2];
        mind[j] = 1e10f;
        sP4[p] = make_float4(px[j], py[j], pz[j], 0.0f);
      }
    }
    __syncthreads();
    float wx = 0.f, wy = 0.f, wz = 0.f;
    if (t < 256) { const float4 w0 = sP4[0]; wx = w0.x; wy = w0.y; wz = w0.z; }
    if (t == 0) {                            // sample 0 = point 0
      const long e0 = (long)g * MM;
      ctr[e0 * 3 + 0] = wx; ctr[e0 * 3 + 1] = wy; ctr[e0 * 3 + 2] = wz;
      fpsIdx[e0] = 0;
    }
    for (int s = 1; s < MM; ++s) {
      if (t < 256) {
        // --- inner: exact r3 numerics ---
        unsigned bb = 0u, bidx = (unsigned)t;
#pragma unroll
        for (int j = 0; j < 16; ++j) {
          const float dx = __fsub_rn(px[j], wx);
          const float dy = __fsub_rn(py[j], wy);
          const float dz = __fsub_rn(pz[j], wz);
          const float d2 = __fadd_rn(__fadd_rn(__fmul_rn(dx, dx), __fmul_rn(dy, dy)), __fmul_rn(dz, dz));
          mind[j] = fminf(mind[j], d2);
          const unsigned mb = __float_as_uint(mind[j]);
          if (mb > bb) { bb = mb; bidx = (unsigned)(t + (j << 8)); }
        }
        const unsigned maxv = wave_umax_u32(bb);
        const unsigned cand = (bb == maxv) ? bidx : 0xffffffffu;
        const unsigned widx_w = wave_umin_u32(cand);
        if (lane == 0)
          sRed[(s & 1) * 4 + wv] = ((unsigned long long)maxv << 32) | (unsigned long long)(~widx_w);
      }
      // Raw barrier: drain LDS only; t0's global stores stay in flight.
      __asm__ __volatile__("s_waitcnt lgkmcnt(0)" ::: "memory");
      __builtin_amdgcn_s_barrier();
      if (t < 256) {
        unsigned long long m = sRed[(s & 1) * 4 + 0];
#pragma unroll
        for (int w = 1; w < 4; ++w) {
          const unsigned long long o = sRed[(s & 1) * 4 + w];
          m = o > m ? o : m;
        }
        const int widx = (int)(~(unsigned)m);
        const float4 wp = sP4[widx];
        wx = wp.x; wy = wp.y; wz = wp.z;
        if (t == 0) {                        // stream centroid s out (lazy drain)
          const long eo = (long)g * MM + s;
          ctr[eo * 3 + 0] = wp.x; ctr[eo * 3 + 1] = wp.y; ctr[eo * 3 + 2] = wp.z;
          fpsIdx[eo] = widx;
          if ((s & 63) == 63)
            __hip_atomic_store(&ctl[CTL_PROG(g)], (unsigned)(s + 1),
                               __ATOMIC_RELEASE, __HIP_MEMORY_SCOPE_AGENT);
        }
      }
    }
    __syncthreads();
    if (t == 0) {
      __hip_atomic_store(&ctl[CTL_PROG(g)], 1024u,
                         __ATOMIC_RELEASE, __HIP_MEMORY_SCOPE_AGENT);
      __hip_atomic_fetch_add(&ctl[CTL_DONE], 1u, __ATOMIC_RELEASE, __HIP_MEMORY_SCOPE_AGENT);
    }
    return;
  }

  // ================= two-team MLP worker (exclusive CU, C=2) =================
  {
    const int team = t >> 9;                 // 0 or 1 (wave-boundary split)
    const int tt = t & 511;
    unsigned char* tb = sBuf + team * 31744; // per-team LDS region (31 KB each)
    __bf16* sMsg = (__bf16*)tb;
    __bf16* sH   = (__bf16*)(tb + 13312);
    int* sSel    = (int*)(tb + 30720);
    int* sCnt    = (int*)(tb + 30976);

    if (t == 0) {  // weights/pos4 gate (once)
      while (__hip_atomic_load(&ctl[CTL_PREP], __ATOMIC_ACQUIRE, __HIP_MEMORY_SCOPE_AGENT) < (unsigned)BB)
        __builtin_amdgcn_s_sleep(8);
    }
    __syncthreads();

    for (;;) {
      if (t == 0) {
        unsigned c;
        const unsigned dn = __hip_atomic_load(&ctl[CTL_DONE], __ATOMIC_ACQUIRE, __HIP_MEMORY_SCOPE_AGENT);
        if (dn >= (unsigned)BB) c = EE;      // FPS done: stop claiming; drain finishes rest
        else c = __hip_atomic_fetch_add(&ctl[CTL_QHEAD], 2u, __ATOMIC_RELAXED, __HIP_MEMORY_SCOPE_AGENT);
        sClaimA = (int)c;
      }
      __syncthreads();                       // loop barrier 1
      const int c0 = sClaimA;
      if (c0 >= EE) return;                  // uniform exit (both teams together)
      const int myc = c0 + team;
      const bool valid = myc < EE;           // wave-uniform (team-dependent)
      const int g = myc & 7, sidx = (myc >> 3) & (MM - 1);
      const int e = g * MM + sidx;
      if (tt == 0 && valid) {                // per-team gate (t==0 and t==512)
        while (__hip_atomic_load(&ctl[CTL_PROG(g)], __ATOMIC_ACQUIRE, __HIP_MEMORY_SCOPE_AGENT)
               <= (unsigned)sidx)
          __builtin_amdgcn_s_sleep(8);
        *sCnt = 0;
      }
      __syncthreads();                       // loop barrier 2
      if (valid) {
        mlp_item(e, g, tt, x, pos4, ctr, fpsIdx, W1t, W2t, W3t, b1, b2, b3,
                 outX, outP, outB, outS, sMsg, sH, sSel, sCnt);  // 6 barriers
      } else {
        // dead path: match mlp_item's 6 barriers exactly (odd-tail only)
        __syncthreads(); __syncthreads(); __syncthreads();
        __syncthreads(); __syncthreads(); __syncthreads();
      }
    }
  }
}

// ---- Kernel B: drain remaining items (runs after A completes; no spins) ----
__global__ __launch_bounds__(512) void drain_kernel(
    const float* __restrict__ x, const float4* __restrict__ pos4,
    const float* __restrict__ ctr, const int* __restrict__ fpsIdx,
    const __bf16* __restrict__ W1t, const __bf16* __restrict__ W2t,
    const __bf16* __restrict__ W3t,
    const float* __restrict__ b1, const float* __restrict__ b2,
    const float* __restrict__ b3, unsigned* __restrict__ ctl,
    float* __restrict__ outX, float* __restrict__ outP,
    float* __restrict__ outB, float* __restrict__ outS) {
  __shared__ __align__(16) __bf16 sMsg[64 * SM];
  __shared__ __align__(16) __bf16 sH[64 * SH];
  __shared__ int sSel[KK];
  __shared__ int sCnt;
  __shared__ int sClaim;
  const int t = threadIdx.x;

  if (t == 0) {
    unsigned c = __hip_atomic_load(&ctl[CTL_QHEAD], __ATOMIC_RELAXED, __HIP_MEMORY_SCOPE_AGENT);
    if (c < (unsigned)EE)   // shortcut avoids atomic herd once queue exhausted
      c = __hip_atomic_fetch_add(&ctl[CTL_QHEAD], 1u, __ATOMIC_RELAXED, __HIP_MEMORY_SCOPE_AGENT);
    sClaim = (int)c;
    sCnt = 0;
  }
  __syncthreads();
  const int c = sClaim;
  if (c >= EE) return;
  const int g = c & 7, sidx = c >> 3;
  mlp_item(g * MM + sidx, g, t, x, pos4, ctr, fpsIdx, W1t, W2t, W3t, b1, b2, b3,
           outX, outP, outB, outS, sMsg, sH, sSel, &sCnt);
}

extern "C" void kernel_launch(void* const* d_in, const int* in_sizes, int n_in,
                              void* d_out, int out_size, void* d_ws, size_t ws_size,
                              hipStream_t stream) {
  const float* x   = (const float*)d_in[0];
  const float* pos = (const float*)d_in[1];
  const float* W1  = (const float*)d_in[4];
  const float* b1  = (const float*)d_in[5];
  const float* W2  = (const float*)d_in[6];
  const float* b2  = (const float*)d_in[7];
  const float* W3  = (const float*)d_in[8];
  const float* b3  = (const float*)d_in[9];

  // Workspace layout (~781 KB)
  char* ws = (char*)d_ws;
  int*    fpsIdx = (int*)(ws);                 // 32768              (ends 32768)
  float*  ctr    = (float*)(ws + 32768);       // 98304              (ends 131072)
  __bf16* W1t    = (__bf16*)(ws + 131072);     // 24576              (ends 155648)
  __bf16* W2t    = (__bf16*)(ws + 155648);     // 32768              (ends 188416)
  __bf16* W3t    = (__bf16*)(ws + 188416);     // 65536              (ends 253952)
  float4* pos4   = (float4*)(ws + 253952);     // 524288             (ends 778240)
  unsigned* ctl  = (unsigned*)(ws + 778240);   // 2048               (ends 780288)

  float* outX = (float*)d_out;                 // [8192,256]
  float* outP = outX + (long)EE * F3;          // [8192,3]
  float* outB = outP + (long)EE * 3;           // [8192]
  float* outS = outB + EE;                     // [8192]

  hipMemsetAsync(ctl, 0, 2048, stream);
  fps_overlap_kernel<<<BB + NWORK, 1024, 0, stream>>>(x, pos, W1, b1, W2, b2, W3, b3,
                                                      fpsIdx, ctr, W1t, W2t, W3t, pos4, ctl,
                                                      outX, outP, outB, outS);
  drain_kernel<<<EE, 512, 0, stream>>>(x, pos4, ctr, fpsIdx, W1t, W2t, W3t,
                                       b1, b2, b3, ctl, outX, outP, outB, outS);
}

// Round 17
// 820.817 us; speedup vs baseline: 1.0409x; 1.0409x over previous
//
#include <hip/hip_runtime.h>
#include <stdint.h>

#define BB 8
#define NN 4096
#define CC 64
#define MM 1024
#define EE (BB*MM)   // 8192 centroids
#define KK 64        // max neighbors
#define F3 256       // output channels
#define SM 104       // msg LDS stride (elements)
#define SH 136       // h LDS stride (elements)
#define CAP 768      // candidate buffer

typedef __bf16 bf16x8 __attribute__((ext_vector_type(8)));
typedef float floatx4 __attribute__((ext_vector_type(4)));

// ---- wave64 reductions via DPP (round-3-verified) ----
#define DPP_MAXSTEP(ctrl, rmask) { \
    unsigned o = (unsigned)__builtin_amdgcn_update_dpp(0, (int)v, ctrl, rmask, 0xf, false); \
    v = v > o ? v : o; }
__device__ __forceinline__ unsigned wave_umax_u32(unsigned v) {
  DPP_MAXSTEP(0x111, 0xf)
  DPP_MAXSTEP(0x112, 0xf)
  DPP_MAXSTEP(0x114, 0xf)
  DPP_MAXSTEP(0x118, 0xf)
  DPP_MAXSTEP(0x142, 0xa)
  DPP_MAXSTEP(0x143, 0xc)
  return (unsigned)__builtin_amdgcn_readlane((int)v, 63);
}
#define DPP_MINSTEP(ctrl, rmask) { \
    unsigned o = (unsigned)__builtin_amdgcn_update_dpp((int)0xffffffffu, (int)v, ctrl, rmask, 0xf, false); \
    v = v < o ? v : o; }
__device__ __forceinline__ unsigned wave_umin_u32(unsigned v) {
  DPP_MINSTEP(0x111, 0xf)
  DPP_MINSTEP(0x112, 0xf)
  DPP_MINSTEP(0x114, 0xf)
  DPP_MINSTEP(0x118, 0xf)
  DPP_MINSTEP(0x142, 0xa)
  DPP_MINSTEP(0x143, 0xc)
  return (unsigned)__builtin_amdgcn_readlane((int)v, 63);
}

// ---- MLP item body (round-3-verified numerics; r5/r11-verified refactor) ----
__device__ __forceinline__ void mlp_item(
    int e, int b, int t,
    const float* __restrict__ x, const float4* __restrict__ pos4,
    const float* __restrict__ ctr, const int* __restrict__ fpsIdx,
    const __bf16* __restrict__ W1t, const __bf16* __restrict__ W2t,
    const __bf16* __restrict__ W3t,
    const float* __restrict__ b1, const float* __restrict__ b2,
    const float* __restrict__ b3,
    float* __restrict__ outX, float* __restrict__ outP,
    float* __restrict__ outB, float* __restrict__ outS,
    __bf16* sMsg, __bf16* sH, int* sSel, int* sCnt) {
  // caller must have set *sCnt = 0 and issued __syncthreads()
  unsigned long long* sDI = (unsigned long long*)sMsg;  // [CAP] packed (d2bits<<32 | idx)
  const int lane = t & 63, wv = t >> 6;

  const float cx = ctr[(long)e * 3 + 0];
  const float cy = ctr[(long)e * 3 + 1];
  const float cz = ctr[(long)e * 3 + 2];
  if (t < 3) outP[(long)e * 3 + t] = ctr[(long)e * 3 + t];
  if (t == 3) { outB[e] = (float)b; outS[e] = (float)(b * NN + fpsIdx[e]); }
  const float R2 = (float)(0.2 * 0.2);

  // Phase A: scan 4096 points; ballot-compact candidates to LDS.
#pragma unroll
  for (int q = 0; q < NN / 512; ++q) {
    const int p = t + q * 512;
    const float4 P = pos4[b * NN + p];
    const float dx = __fsub_rn(cx, P.x);
    const float dy = __fsub_rn(cy, P.y);
    const float dz = __fsub_rn(cz, P.z);
    const float d2 = __fadd_rn(__fadd_rn(__fmul_rn(dx, dx), __fmul_rn(dy, dy)), __fmul_rn(dz, dz));
    const bool v = d2 < R2;
    const unsigned long long mask = __ballot(v);
    int wbase = 0;
    if (lane == 0 && mask) wbase = atomicAdd(sCnt, (int)__popcll(mask));
    wbase = __shfl(wbase, 0);
    if (v) {
      const int off = wbase + (int)__popcll(mask & ((1ull << lane) - 1ull));
      if (off < CAP)
        sDI[off] = ((unsigned long long)__float_as_uint(d2) << 32) | (unsigned)p;
    }
  }
  __syncthreads();
  int cnt = *sCnt; cnt = cnt > CAP ? CAP : cnt;
  const int nsel = cnt < KK ? cnt : KK;

  // Phase B: parallel rank selection.
  for (int i = t; i < cnt; i += 512) {
    const unsigned long long my = sDI[i];
    int rank = 0;
#pragma unroll 8
    for (int j = 0; j < cnt; ++j) rank += (sDI[j] < my) ? 1 : 0;
    if (rank < KK) sSel[rank] = (int)(unsigned)(my & 0xffffffffu);
  }
  __syncthreads();
  cnt = nsel;

  // Phase C: stage msg tile into LDS as bf16.
  {
    const int r = t >> 3, p = t & 7;
    float4 a = make_float4(0.f, 0.f, 0.f, 0.f), c4 = a;
    if (r < cnt) {
      const float* xr = x + (long)(b * NN + sSel[r]) * CC + p * 8;
      a  = *(const float4*)xr;
      c4 = *(const float4*)(xr + 4);
    }
    __bf16 o[8] = {(__bf16)a.x, (__bf16)a.y, (__bf16)a.z, (__bf16)a.w,
                   (__bf16)c4.x, (__bf16)c4.y, (__bf16)c4.z, (__bf16)c4.w};
    *(uint4*)&sMsg[r * SM + p * 8] = *(uint4*)o;
  }
  if (t < 64) {
    const int r = t;
    __bf16 d0 = (__bf16)0.0f, d1 = (__bf16)0.0f, d2v = (__bf16)0.0f;
    if (r < cnt) {
      const float4 P = pos4[b * NN + sSel[r]];
      d0  = (__bf16)__fsub_rn(P.x, cx);
      d1  = (__bf16)__fsub_rn(P.y, cy);
      d2v = (__bf16)__fsub_rn(P.z, cz);
    }
    sMsg[r * SM + 64] = d0;
    sMsg[r * SM + 65] = d1;
    sMsg[r * SM + 66] = d2v;
    for (int c = 67; c < SM; ++c) sMsg[r * SM + c] = (__bf16)0.0f;
  }
  __syncthreads();

  const int l15 = lane & 15, quad = lane >> 4;
  // layer 1
  {
    floatx4 acc[4] = {};
    const __bf16* wrow = W1t + (wv * 16 + l15) * 96;
#pragma unroll
    for (int ks = 0; ks < 3; ++ks) {
      const bf16x8 bfrag = *(const bf16x8*)(wrow + ks * 32 + quad * 8);
#pragma unroll
      for (int mt = 0; mt < 4; ++mt) {
        const bf16x8 afrag = *(const bf16x8*)&sMsg[(mt * 16 + l15) * SM + ks * 32 + quad * 8];
        acc[mt] = __builtin_amdgcn_mfma_f32_16x16x32_bf16(afrag, bfrag, acc[mt], 0, 0, 0);
      }
    }
    const int col = wv * 16 + l15;
    const float bias = b1[col];
#pragma unroll
    for (int mt = 0; mt < 4; ++mt)
#pragma unroll
      for (int rg = 0; rg < 4; ++rg) {
        const int row = mt * 16 + quad * 4 + rg;
        float v = acc[mt][rg] + bias;
        v = v > 0.0f ? v : 0.0f;
        sH[row * SH + col] = (__bf16)v;
      }
  }
  __syncthreads();
  // layer 2 (in place on sH)
  {
    floatx4 acc[4] = {};
    const __bf16* wrow = W2t + (wv * 16 + l15) * 128;
#pragma unroll
    for (int ks = 0; ks < 4; ++ks) {
      const bf16x8 bfrag = *(const bf16x8*)(wrow + ks * 32 + quad * 8);
#pragma unroll
      for (int mt = 0; mt < 4; ++mt) {
        const bf16x8 afrag = *(const bf16x8*)&sH[(mt * 16 + l15) * SH + ks * 32 + quad * 8];
        acc[mt] = __builtin_amdgcn_mfma_f32_16x16x32_bf16(afrag, bfrag, acc[mt], 0, 0, 0);
      }
    }
    __syncthreads();
    const int col = wv * 16 + l15;
    const float bias = b2[col];
#pragma unroll
    for (int mt = 0; mt < 4; ++mt)
#pragma unroll
      for (int rg = 0; rg < 4; ++rg) {
        const int row = mt * 16 + quad * 4 + rg;
        float v = acc[mt][rg] + bias;
        v = v > 0.0f ? v : 0.0f;
        sH[row * SH + col] = (__bf16)v;
      }
  }
  __syncthreads();
  // layer 3 + fused masked max
  {
    floatx4 acc[2][4] = {};
#pragma unroll
    for (int ks = 0; ks < 4; ++ks) {
      bf16x8 afrag[4];
#pragma unroll
      for (int mt = 0; mt < 4; ++mt)
        afrag[mt] = *(const bf16x8*)&sH[(mt * 16 + l15) * SH + ks * 32 + quad * 8];
#pragma unroll
      for (int i = 0; i < 2; ++i) {
        const bf16x8 bfrag = *(const bf16x8*)(W3t + ((wv * 2 + i) * 16 + l15) * 128 + ks * 32 + quad * 8);
#pragma unroll
        for (int mt = 0; mt < 4; ++mt)
          acc[i][mt] = __builtin_amdgcn_mfma_f32_16x16x32_bf16(afrag[mt], bfrag, acc[i][mt], 0, 0, 0);
      }
    }
#pragma unroll
    for (int i = 0; i < 2; ++i) {
      const int col = (wv * 2 + i) * 16 + l15;
      const float bias = b3[col];
      float mx = 0.0f;
#pragma unroll
      for (int mt = 0; mt < 4; ++mt)
#pragma unroll
        for (int rg = 0; rg < 4; ++rg) {
          const int row = mt * 16 + quad * 4 + rg;
          float v = acc[i][mt][rg] + bias;
          v = v > 0.0f ? v : 0.0f;
          if (row < cnt) mx = fmaxf(mx, v);
        }
      mx = fmaxf(mx, __shfl_xor(mx, 16));
      mx = fmaxf(mx, __shfl_xor(mx, 32));
      if (quad == 0) outX[(long)e * F3 + col] = mx;
    }
  }
}

// ctl layout (dwords; each counter on its own 128B line); memset 2048 B:
#define CTL_PREP 0
#define CTL_PROG(g) (32*((g)+1))
#define CTL_QHEAD 320
#define CTL_DONE 352

// ---- Kernel A: grid 256, LDS padded to 82 KB => HW guarantees 1 block/CU.
//      MEASURED OPTIMUM of the 16-round structure space (r11: 813.8 us total).
//      blocks 0..7: FPS producers; blocks 8..255: one-team persistent workers.
//      The design-space map (r4-r16): sequential = 825-828; this = 813.8;
//      all other overlap variants (2-team, lazy barrier, LDS-ring flush,
//      reduced grid) land 818-854. FPS under any substantial MFMA co-load runs
//      ~750 vs 577 solo (chip-wide clock/power, by elimination: co-residency
//      fixed via pad, store-drain falsified r13, idle-CU relief falsified r15);
//      worker per-CU throughput pins at ~0.032 items/us under load (r13/r15/r16)
//      => drain tail ~60 us is structural. Do not touch.
__global__ __launch_bounds__(512) void fps_overlap_kernel(
    const float* __restrict__ x, const float* __restrict__ pos,
    const float* __restrict__ W1, const float* __restrict__ b1,
    const float* __restrict__ W2, const float* __restrict__ b2,
    const float* __restrict__ W3, const float* __restrict__ b3,
    int* __restrict__ fpsIdx, float* __restrict__ ctr,
    __bf16* __restrict__ W1t, __bf16* __restrict__ W2t, __bf16* __restrict__ W3t,
    float4* __restrict__ pos4, unsigned* __restrict__ ctl,
    float* __restrict__ outX, float* __restrict__ outP,
    float* __restrict__ outB, float* __restrict__ outS) {
  __shared__ __align__(16) unsigned char sBuf[83968];  // 82 KB pad => exclusive CU
  __shared__ int sClaim;

  const int t = threadIdx.x;
  const int blk = blockIdx.x;

  if (blk < BB) {
    // ================= FPS producer (graph g), r3-exact 4-wave loop =================
    const int g = blk;
    float4* sP4 = (float4*)sBuf;
    unsigned long long* sRed = (unsigned long long*)(sBuf + 65536);  // [2][4]

    // prep slice: 94208 items over 8 blocks = 11776 each
    for (int k = g * 11776 + t; k < (g + 1) * 11776; k += 512) {
      if (k < 12288) {
        const int n = k / 96, kk = k % 96;
        W1t[k] = (kk < 67) ? (__bf16)W1[kk * 128 + n] : (__bf16)0.0f;
      } else if (k < 28672) {
        const int i = k - 12288, n = i / 128, kk = i % 128;
        W2t[i] = (__bf16)W2[kk * 128 + n];
      } else if (k < 61440) {
        const int i = k - 28672, n = i / 128, kk = i % 128;
        W3t[i] = (__bf16)W3[kk * 256 + n];
      } else {
        const int i = k - 61440;
        pos4[i] = make_float4(pos[(long)i * 3 + 0], pos[(long)i * 3 + 1],
                              pos[(long)i * 3 + 2], 0.0f);
      }
    }
    __threadfence();
    __syncthreads();
    if (t == 0)
      __hip_atomic_fetch_add(&ctl[CTL_PREP], 1u, __ATOMIC_RELEASE, __HIP_MEMORY_SCOPE_AGENT);

    __builtin_amdgcn_s_setprio(1);

    const int lane = t & 63, wv = t >> 6;    // working waves 0..3 (t<256)
    float px[16], py[16], pz[16], mind[16];
    if (t < 256) {
#pragma unroll
      for (int j = 0; j < 16; ++j) {
        const int p = t + (j << 8);
        const long base = ((long)g * NN + p) * 3;
        px[j] = pos[base + 0];
        py[j] = pos[base + 1];
        pz[j] = pos[base + 2];
        mind[j] = 1e10f;
        sP4[p] = make_float4(px[j], py[j], pz[j], 0.0f);
      }
    }
    __syncthreads();
    float wx = 0.f, wy = 0.f, wz = 0.f;
    if (t < 256) { const float4 w0 = sP4[0]; wx = w0.x; wy = w0.y; wz = w0.z; }
    if (t == 0) {                            // sample 0 = point 0
      const long e0 = (long)g * MM;
      ctr[e0 * 3 + 0] = wx; ctr[e0 * 3 + 1] = wy; ctr[e0 * 3 + 2] = wz;
      fpsIdx[e0] = 0;
    }
    for (int s = 1; s < MM; ++s) {
      if (t < 256) {
        // --- inner: exact r3 numerics ---
        unsigned bb = 0u, bidx = (unsigned)t;
#pragma unroll
        for (int j = 0; j < 16; ++j) {
          const float dx = __fsub_rn(px[j], wx);
          const float dy = __fsub_rn(py[j], wy);
          const float dz = __fsub_rn(pz[j], wz);
          const float d2 = __fadd_rn(__fadd_rn(__fmul_rn(dx, dx), __fmul_rn(dy, dy)), __fmul_rn(dz, dz));
          mind[j] = fminf(mind[j], d2);
          const unsigned mb = __float_as_uint(mind[j]);
          if (mb > bb) { bb = mb; bidx = (unsigned)(t + (j << 8)); }
        }
        const unsigned maxv = wave_umax_u32(bb);
        const unsigned cand = (bb == maxv) ? bidx : 0xffffffffu;
        const unsigned widx_w = wave_umin_u32(cand);
        if (lane == 0)
          sRed[(s & 1) * 4 + wv] = ((unsigned long long)maxv << 32) | (unsigned long long)(~widx_w);
      }
      __syncthreads();                       // idle waves 4..7 participate (uniform count)
      if (t < 256) {
        unsigned long long m = sRed[(s & 1) * 4 + 0];
#pragma unroll
        for (int w = 1; w < 4; ++w) {
          const unsigned long long o = sRed[(s & 1) * 4 + w];
          m = o > m ? o : m;
        }
        const int widx = (int)(~(unsigned)m);
        const float4 wp = sP4[widx];
        wx = wp.x; wy = wp.y; wz = wp.z;
        if (t == 0) {                        // stream centroid s out
          const long eo = (long)g * MM + s;
          ctr[eo * 3 + 0] = wp.x; ctr[eo * 3 + 1] = wp.y; ctr[eo * 3 + 2] = wp.z;
          fpsIdx[eo] = widx;
          if ((s & 31) == 31)                // publish every 32 (release orders prior stores)
            __hip_atomic_store(&ctl[CTL_PROG(g)], (unsigned)(s + 1),
                               __ATOMIC_RELEASE, __HIP_MEMORY_SCOPE_AGENT);
        }
      }
    }
    if (t == 0)
      __hip_atomic_fetch_add(&ctl[CTL_DONE], 1u, __ATOMIC_RELEASE, __HIP_MEMORY_SCOPE_AGENT);
    return;
  }

  // ================= persistent MLP worker (exclusive CU) =================
  {
    __bf16* sMsg = (__bf16*)sBuf;
    __bf16* sH   = (__bf16*)(sBuf + 13312);
    int* sSel    = (int*)(sBuf + 30720);
    int* sCnt    = (int*)(sBuf + 30976);

    if (t == 0) {  // weights/pos4 gate (once)
      while (__hip_atomic_load(&ctl[CTL_PREP], __ATOMIC_ACQUIRE, __HIP_MEMORY_SCOPE_AGENT) < (unsigned)BB)
        __builtin_amdgcn_s_sleep(8);
    }
    __syncthreads();

    for (;;) {
      if (t == 0) {
        unsigned c;
        const unsigned dn = __hip_atomic_load(&ctl[CTL_DONE], __ATOMIC_ACQUIRE, __HIP_MEMORY_SCOPE_AGENT);
        if (dn >= (unsigned)BB) c = EE;          // FPS done: stop claiming; drain finishes rest
        else c = __hip_atomic_fetch_add(&ctl[CTL_QHEAD], 1u, __ATOMIC_RELAXED, __HIP_MEMORY_SCOPE_AGENT);
        sClaim = (int)c;
      }
      __syncthreads();
      const int c = sClaim;
      if (c >= EE) return;
      const int g = c & 7, sidx = c >> 3;        // interleave across graphs = production order
      const int e = g * MM + sidx;
      if (t == 0) {
        while (__hip_atomic_load(&ctl[CTL_PROG(g)], __ATOMIC_ACQUIRE, __HIP_MEMORY_SCOPE_AGENT)
               <= (unsigned)sidx)
          __builtin_amdgcn_s_sleep(8);
        *sCnt = 0;
      }
      __syncthreads();
      mlp_item(e, g, t, x, pos4, ctr, fpsIdx, W1t, W2t, W3t, b1, b2, b3,
               outX, outP, outB, outS, sMsg, sH, sSel, sCnt);
      // loop-top barrier re-joins all threads before LDS reuse
    }
  }
}

// ---- Kernel B: drain remaining items (runs after A completes; no spins) ----
__global__ __launch_bounds__(512) void drain_kernel(
    const float* __restrict__ x, const float4* __restrict__ pos4,
    const float* __restrict__ ctr, const int* __restrict__ fpsIdx,
    const __bf16* __restrict__ W1t, const __bf16* __restrict__ W2t,
    const __bf16* __restrict__ W3t,
    const float* __restrict__ b1, const float* __restrict__ b2,
    const float* __restrict__ b3, unsigned* __restrict__ ctl,
    float* __restrict__ outX, float* __restrict__ outP,
    float* __restrict__ outB, float* __restrict__ outS) {
  __shared__ __align__(16) __bf16 sMsg[64 * SM];
  __shared__ __align__(16) __bf16 sH[64 * SH];
  __shared__ int sSel[KK];
  __shared__ int sCnt;
  __shared__ int sClaim;
  const int t = threadIdx.x;

  if (t == 0) {
    unsigned c = __hip_atomic_load(&ctl[CTL_QHEAD], __ATOMIC_RELAXED, __HIP_MEMORY_SCOPE_AGENT);
    if (c < (unsigned)EE)   // shortcut avoids atomic herd once queue exhausted
      c = __hip_atomic_fetch_add(&ctl[CTL_QHEAD], 1u, __ATOMIC_RELAXED, __HIP_MEMORY_SCOPE_AGENT);
    sClaim = (int)c;
    sCnt = 0;
  }
  __syncthreads();
  const int c = sClaim;
  if (c >= EE) return;
  const int g = c & 7, sidx = c >> 3;
  mlp_item(g * MM + sidx, g, t, x, pos4, ctr, fpsIdx, W1t, W2t, W3t, b1, b2, b3,
           outX, outP, outB, outS, sMsg, sH, sSel, &sCnt);
}

extern "C" void kernel_launch(void* const* d_in, const int* in_sizes, int n_in,
                              void* d_out, int out_size, void* d_ws, size_t ws_size,
                              hipStream_t stream) {
  const float* x   = (const float*)d_in[0];
  const float* pos = (const float*)d_in[1];
  const float* W1  = (const float*)d_in[4];
  const float* b1  = (const float*)d_in[5];
  const float* W2  = (const float*)d_in[6];
  const float* b2  = (const float*)d_in[7];
  const float* W3  = (const float*)d_in[8];
  const float* b3  = (const float*)d_in[9];

  // Workspace layout (~781 KB)
  char* ws = (char*)d_ws;
  int*    fpsIdx = (int*)(ws);                 // 32768              (ends 32768)
  float*  ctr    = (float*)(ws + 32768);       // 98304              (ends 131072)
  __bf16* W1t    = (__bf16*)(ws + 131072);     // 24576              (ends 155648)
  __bf16* W2t    = (__bf16*)(ws + 155648);     // 32768              (ends 188416)
  __bf16* W3t    = (__bf16*)(ws + 188416);     // 65536              (ends 253952)
  float4* pos4   = (float4*)(ws + 253952);     // 524288             (ends 778240)
  unsigned* ctl  = (unsigned*)(ws + 778240);   // 2048               (ends 780288)

  float* outX = (float*)d_out;                 // [8192,256]
  float* outP = outX + (long)EE * F3;          // [8192,3]
  float* outB = outP + (long)EE * 3;           // [8192]
  float* outS = outB + EE;                     // [8192]

  hipMemsetAsync(ctl, 0, 2048, stream);
  fps_overlap_kernel<<<256, 512, 0, stream>>>(x, pos, W1, b1, W2, b2, W3, b3,
                                              fpsIdx, ctr, W1t, W2t, W3t, pos4, ctl,
                                              outX, outP, outB, outS);
  drain_kernel<<<EE, 512, 0, stream>>>(x, pos4, ctr, fpsIdx, W1t, W2t, W3t,
                                       b1, b2, b3, ctl, outX, outP, outB, outS);
}